// Round 11
// baseline (429.539 us; speedup 1.0000x reference)
//
#include <hip/hip_runtime.h>
#include <hip/hip_bf16.h>
#include <math.h>

#define NPTS 500000
#define M_ASSIGN 400000
#define WPR 15625   // 500000/32 words per bitmap row
#define NWIN 31250  // NPTS/16 windows of 16 points (exact)
#define NTILE 7812  // full 64-point tiles; tail = windows 31248,31249

// workspace layout (float units)
constexpr int    OFF_ACC      = 0;        // [0]=nll_sum [1]=valid_cnt [2]=l1_sum [3]=cos_sum [4]=mask_sum
constexpr int    OFF_SUM      = 64;       // 64 BN sums (of raw h, no b1)
constexpr int    OFF_SQ       = 128;      // 64 BN sumsq
constexpr int    OFF_BITMAP   = 320;      // 2,000,000 uint32
constexpr int    OFF_SEGPRED  = 2000320;  // 500,000 int
constexpr int    OFF_PROBS    = 2500448;  // 10,000,000 float

typedef __attribute__((ext_vector_type(8))) short short8v;
typedef __attribute__((ext_vector_type(4))) float f32x4;

__device__ inline unsigned bf16rne(float x) {
  unsigned u = __float_as_uint(x);
  return (u + 0x7fffu + ((u >> 16) & 1u)) >> 16;
}
__device__ inline unsigned pk2(float lo, float hi) {
  return bf16rne(lo) | (bf16rne(hi) << 16);
}

// async global->LDS, 16B per lane (dest = wave-uniform base + lane*16)
__device__ inline void gload16(const float* g, float* l) {
  __builtin_amdgcn_global_load_lds(
      (const __attribute__((address_space(1))) void*)g,
      (__attribute__((address_space(3))) void*)l, 16, 0, 0);
}

// ---------------------------------------------------------------------------
// K1 (MFMA + async-LDS dbuf): [h | seg logits] = feat @ [w1 | seg_w]
// NO h store. Fused: BN partials, softmax->probs, argmax->segp, NLL.
// ---------------------------------------------------------------------------
__global__ __launch_bounds__(256) void gemm_kernel(
    const float* __restrict__ feat, const float* __restrict__ w1,
    const float* __restrict__ seg_w, const float* __restrict__ seg_b,
    const int* __restrict__ segment, float* __restrict__ ws)
{
  __shared__ float fsbuf[2][4096];   // 2 x 16KB

  float* acc   = ws + OFF_ACC;
  int*   segp  = (int*)(ws + OFF_SEGPRED);
  float* probs = ws + OFF_PROBS;

  const int tid  = threadIdx.x;
  const int lane = tid & 63;
  const int col  = lane & 15;
  const int kg   = lane >> 4;
  const int wv   = tid >> 6;

  // ---- build B fragments (once per block) ----
  auto mkb = [&](int t, int ks) -> short8v {
    union { short8v v; unsigned short u[8]; } bu;
    #pragma unroll
    for (int i = 0; i < 8; ++i) {
      const int k = ks * 32 + kg * 8 + i;
      float v;
      if (t < 4)       v = w1[k * 64 + t * 16 + col];
      else if (t == 4) v = seg_w[k * 20 + col];
      else             v = (col < 4) ? seg_w[k * 20 + 16 + col] : 0.f;
      bu.u[i] = (unsigned short)bf16rne(v);
    }
    return bu.v;
  };
  const short8v B00 = mkb(0,0), B01 = mkb(0,1);
  const short8v B10 = mkb(1,0), B11 = mkb(1,1);
  const short8v B20 = mkb(2,0), B21 = mkb(2,1);
  const short8v B30 = mkb(3,0), B31 = mkb(3,1);
  const short8v B40 = mkb(4,0), B41 = mkb(4,1);
  const short8v B50 = mkb(5,0), B51 = mkb(5,1);

  const float sb4 = seg_b[col];
  const float sb5 = (col < 4) ? seg_b[16 + col] : 0.f;

  float bnsum[4] = {0.f, 0.f, 0.f, 0.f};
  float bnsq[4]  = {0.f, 0.f, 0.f, 0.f};
  float nll_acc = 0.f, vld_acc = 0.f;

  auto do_window = [&](int W, const short8v& A0v, const short8v& A1v) {
    f32x4 ac0 = {0.f,0.f,0.f,0.f}, ac1 = ac0, ac2 = ac0, ac3 = ac0;
    f32x4 ac4 = {sb4, sb4, sb4, sb4};
    f32x4 ac5 = {sb5, sb5, sb5, sb5};
    ac0 = __builtin_amdgcn_mfma_f32_16x16x32_bf16(A0v, B00, ac0, 0, 0, 0);
    ac0 = __builtin_amdgcn_mfma_f32_16x16x32_bf16(A1v, B01, ac0, 0, 0, 0);
    ac1 = __builtin_amdgcn_mfma_f32_16x16x32_bf16(A0v, B10, ac1, 0, 0, 0);
    ac1 = __builtin_amdgcn_mfma_f32_16x16x32_bf16(A1v, B11, ac1, 0, 0, 0);
    ac2 = __builtin_amdgcn_mfma_f32_16x16x32_bf16(A0v, B20, ac2, 0, 0, 0);
    ac2 = __builtin_amdgcn_mfma_f32_16x16x32_bf16(A1v, B21, ac2, 0, 0, 0);
    ac3 = __builtin_amdgcn_mfma_f32_16x16x32_bf16(A0v, B30, ac3, 0, 0, 0);
    ac3 = __builtin_amdgcn_mfma_f32_16x16x32_bf16(A1v, B31, ac3, 0, 0, 0);
    ac4 = __builtin_amdgcn_mfma_f32_16x16x32_bf16(A0v, B40, ac4, 0, 0, 0);
    ac4 = __builtin_amdgcn_mfma_f32_16x16x32_bf16(A1v, B41, ac4, 0, 0, 0);
    ac5 = __builtin_amdgcn_mfma_f32_16x16x32_bf16(A0v, B50, ac5, 0, 0, 0);
    ac5 = __builtin_amdgcn_mfma_f32_16x16x32_bf16(A1v, B51, ac5, 0, 0, 0);

    #pragma unroll
    for (int r = 0; r < 4; ++r) {
      bnsum[0] += ac0[r]; bnsq[0] += ac0[r] * ac0[r];
      bnsum[1] += ac1[r]; bnsq[1] += ac1[r] * ac1[r];
      bnsum[2] += ac2[r]; bnsq[2] += ac2[r] * ac2[r];
      bnsum[3] += ac3[r]; bnsq[3] += ac3[r] * ac3[r];

      const int p = W * 16 + kg * 4 + r;
      const int seg = segment[p];
      const float l4 = ac4[r];
      const float l5 = ac5[r];
      float mv; int mi;
      if (col < 4 && l5 > l4) { mv = l5; mi = 16 + col; }
      else                    { mv = l4; mi = col; }
      #pragma unroll
      for (int msk = 1; msk < 16; msk <<= 1) {
        const float om = __shfl_xor(mv, msk);
        const int   oi = __shfl_xor(mi, msk);
        if (om > mv || (om == mv && oi < mi)) { mv = om; mi = oi; }
      }
      const float e4 = __expf(l4 - mv);
      const float e5 = (col < 4) ? __expf(l5 - mv) : 0.f;
      const int sidx = seg < 0 ? 0 : (seg > 19 ? 19 : seg);
      float sp = e4 + e5;
      float lv = (col == sidx ? l4 : 0.f) + ((col < 4 && (16 + col) == sidx) ? l5 : 0.f);
      #pragma unroll
      for (int msk = 1; msk < 16; msk <<= 1) {
        sp += __shfl_xor(sp, msk);
        lv += __shfl_xor(lv, msk);
      }
      const float inv = 1.f / sp;
      probs[(size_t)p * 20 + col] = e4 * inv;
      if (col < 4) probs[(size_t)p * 20 + 16 + col] = e5 * inv;
      if (col == 0) {
        segp[p] = mi;
        const bool svalid = (seg != -1);
        nll_acc += svalid ? (mv + __logf(sp) - lv) : 0.f;
        vld_acc += svalid ? 1.f : 0.f;
      }
    }
  };

  auto stage = [&](float* buf, int tile) {
    const float* base = feat + (size_t)tile * 64 * 64;
    #pragma unroll
    for (int j = 0; j < 4; ++j) {
      const int u = j * 256 + tid;
      const int p = u >> 4;
      const int kl = (u & 15) << 2;
      const int kgx = kl ^ ((p & 15) << 2);
      gload16(base + p * 64 + kgx, buf + u * 4);
    }
  };
  auto lds4 = [&](const float* buf, int p, int k) -> f32x4 {
    return *(const f32x4*)(buf + p * 64 + (k ^ ((p & 15) << 2)));
  };

  int cur = 0;
  const int t0 = blockIdx.x;
  if (t0 < NTILE) {
    stage(fsbuf[0], t0);
    __syncthreads();
    for (int t = t0; t < NTILE; t += gridDim.x) {
      const int tn = t + gridDim.x;
      if (tn < NTILE) stage(fsbuf[cur ^ 1], tn);

      const float* bufc = fsbuf[cur];
      const int p = wv * 16 + col;
      const f32x4 r0 = lds4(bufc, p, kg * 8);
      const f32x4 r1 = lds4(bufc, p, kg * 8 + 4);
      const f32x4 r2 = lds4(bufc, p, 32 + kg * 8);
      const f32x4 r3 = lds4(bufc, p, 32 + kg * 8 + 4);
      union { short8v v; unsigned u[4]; } A0, A1;
      A0.u[0] = pk2(r0[0], r0[1]); A0.u[1] = pk2(r0[2], r0[3]);
      A0.u[2] = pk2(r1[0], r1[1]); A0.u[3] = pk2(r1[2], r1[3]);
      A1.u[0] = pk2(r2[0], r2[1]); A1.u[1] = pk2(r2[2], r2[3]);
      A1.u[2] = pk2(r3[0], r3[1]); A1.u[3] = pk2(r3[2], r3[3]);

      do_window(t * 4 + wv, A0.v, A1.v);

      __syncthreads();
      cur ^= 1;
    }
  }

  // ---- tail: windows 31248, 31249 ----
  if (blockIdx.x == 0 && wv < 2) {
    const int W = NWIN - 2 + wv;
    const float* fp = feat + (size_t)(W * 16 + col) * 64 + kg * 8;
    const f32x4 a0 = *(const f32x4*)(fp);
    const f32x4 a1 = *(const f32x4*)(fp + 4);
    const f32x4 a2 = *(const f32x4*)(fp + 32);
    const f32x4 a3 = *(const f32x4*)(fp + 36);
    union { short8v v; unsigned u[4]; } A0, A1;
    A0.u[0] = pk2(a0[0], a0[1]); A0.u[1] = pk2(a0[2], a0[3]);
    A0.u[2] = pk2(a1[0], a1[1]); A0.u[3] = pk2(a1[2], a1[3]);
    A1.u[0] = pk2(a2[0], a2[1]); A1.u[1] = pk2(a2[2], a2[3]);
    A1.u[2] = pk2(a3[0], a3[1]); A1.u[3] = pk2(a3[2], a3[3]);
    do_window(W, A0.v, A1.v);
  }

  // ---- BN reduce ----
  #pragma unroll
  for (int t = 0; t < 4; ++t) {
    float s = bnsum[t], q = bnsq[t];
    s += __shfl_down(s, 32); s += __shfl_down(s, 16);
    q += __shfl_down(q, 32); q += __shfl_down(q, 16);
    if (lane < 16) {
      atomicAdd(&ws[OFF_SUM + t * 16 + lane], s);
      atomicAdd(&ws[OFF_SQ  + t * 16 + lane], q);
    }
  }
  float s = nll_acc, v = vld_acc;
  #pragma unroll
  for (int o = 32; o > 0; o >>= 1) { s += __shfl_down(s, o); v += __shfl_down(v, o); }
  if (lane == 0) { atomicAdd(&acc[0], s); atomicAdd(&acc[1], v); }
}

// ---------------------------------------------------------------------------
// K2 (MFMA): recompute h = feat@w1, BN+ReLU in-register, w2 head via col-group
// butterflies, L1/cosine partials. No h buffer anywhere.
// ---------------------------------------------------------------------------
__global__ __launch_bounds__(256) void bias_kernel(
    const float* __restrict__ feat, const float* __restrict__ w1,
    const float* __restrict__ gamma, const float* __restrict__ beta,
    const float* __restrict__ w2, const float* __restrict__ b2,
    const float* __restrict__ coord, const float* __restrict__ cent,
    const int* __restrict__ instance, float* __restrict__ ws)
{
  __shared__ float fsbuf[2][4096];
  __shared__ float scs[64], shs[64];
  float* acc = ws + OFF_ACC;

  const int tid  = threadIdx.x;
  const int lane = tid & 63;
  const int col  = lane & 15;
  const int kg   = lane >> 4;
  const int wv   = tid >> 6;

  if (tid < 64) {
    const float mu  = ws[OFF_SUM + tid] * (1.f / NPTS);
    const float var = ws[OFF_SQ  + tid] * (1.f / NPTS) - mu * mu;
    const float sc = gamma[tid] * rsqrtf(var + 0.001f);
    scs[tid] = sc;
    shs[tid] = beta[tid] - mu * sc;   // b1 cancels through BN
  }
  __syncthreads();

  auto mkb = [&](int t, int ks) -> short8v {
    union { short8v v; unsigned short u[8]; } bu;
    #pragma unroll
    for (int i = 0; i < 8; ++i) {
      const int k = ks * 32 + kg * 8 + i;
      bu.u[i] = (unsigned short)bf16rne(w1[k * 64 + t * 16 + col]);
    }
    return bu.v;
  };
  const short8v B00 = mkb(0,0), B01 = mkb(0,1);
  const short8v B10 = mkb(1,0), B11 = mkb(1,1);
  const short8v B20 = mkb(2,0), B21 = mkb(2,1);
  const short8v B30 = mkb(3,0), B31 = mkb(3,1);

  // per-lane BN + w2 constants for its 4 channels (t*16+col)
  float sc4[4], sh4[4], w2x[4], w2y[4], w2z[4];
  #pragma unroll
  for (int t = 0; t < 4; ++t) {
    const int c = t * 16 + col;
    sc4[t] = scs[c]; sh4[t] = shs[c];
    w2x[t] = w2[c * 3 + 0]; w2y[t] = w2[c * 3 + 1]; w2z[t] = w2[c * 3 + 2];
  }
  const float b2x = b2[0], b2y = b2[1], b2z = b2[2];

  float l1_acc = 0.f, cos_acc = 0.f, mk_acc = 0.f;

  auto do_window = [&](int W, const short8v& A0v, const short8v& A1v) {
    // prefetch loss inputs: lane col<4 handles point W*16 + kg*4 + col
    float cx=0,cy=0,cz=0,ex=0,ey=0,ez=0; int inst = -1;
    const int myp = W * 16 + kg * 4 + col;
    if (col < 4) {
      cx = coord[(size_t)myp*3+0]; cy = coord[(size_t)myp*3+1]; cz = coord[(size_t)myp*3+2];
      ex = cent[(size_t)myp*3+0];  ey = cent[(size_t)myp*3+1];  ez = cent[(size_t)myp*3+2];
      inst = instance[myp];
    }

    f32x4 ac0 = {0.f,0.f,0.f,0.f}, ac1 = ac0, ac2 = ac0, ac3 = ac0;
    ac0 = __builtin_amdgcn_mfma_f32_16x16x32_bf16(A0v, B00, ac0, 0, 0, 0);
    ac0 = __builtin_amdgcn_mfma_f32_16x16x32_bf16(A1v, B01, ac0, 0, 0, 0);
    ac1 = __builtin_amdgcn_mfma_f32_16x16x32_bf16(A0v, B10, ac1, 0, 0, 0);
    ac1 = __builtin_amdgcn_mfma_f32_16x16x32_bf16(A1v, B11, ac1, 0, 0, 0);
    ac2 = __builtin_amdgcn_mfma_f32_16x16x32_bf16(A0v, B20, ac2, 0, 0, 0);
    ac2 = __builtin_amdgcn_mfma_f32_16x16x32_bf16(A1v, B21, ac2, 0, 0, 0);
    ac3 = __builtin_amdgcn_mfma_f32_16x16x32_bf16(A0v, B30, ac3, 0, 0, 0);
    ac3 = __builtin_amdgcn_mfma_f32_16x16x32_bf16(A1v, B31, ac3, 0, 0, 0);

    float bpx = 0.f, bpy = 0.f, bpz = 0.f;   // this lane's point bias (col<4)
    #pragma unroll
    for (int r = 0; r < 4; ++r) {
      const float h0 = fmaxf(fmaf(ac0[r], sc4[0], sh4[0]), 0.f);
      const float h1 = fmaxf(fmaf(ac1[r], sc4[1], sh4[1]), 0.f);
      const float h2 = fmaxf(fmaf(ac2[r], sc4[2], sh4[2]), 0.f);
      const float h3 = fmaxf(fmaf(ac3[r], sc4[3], sh4[3]), 0.f);
      float bx = h0 * w2x[0] + h1 * w2x[1] + h2 * w2x[2] + h3 * w2x[3];
      float by = h0 * w2y[0] + h1 * w2y[1] + h2 * w2y[2] + h3 * w2y[3];
      float bz = h0 * w2z[0] + h1 * w2z[1] + h2 * w2z[2] + h3 * w2z[3];
      #pragma unroll
      for (int msk = 1; msk < 16; msk <<= 1) {
        bx += __shfl_xor(bx, msk);
        by += __shfl_xor(by, msk);
        bz += __shfl_xor(bz, msk);
      }
      if (col == r) { bpx = bx; bpy = by; bpz = bz; }
    }

    if (col < 4) {
      const float bx = bpx + b2x, by = bpy + b2y, bz = bpz + b2z;
      const float gx = ex - cx, gy = ey - cy, gz = ez - cz;
      const float dx = bx - gx, dy = by - gy, dz = bz - gz;
      const float l1 = fabsf(dx) + fabsf(dy) + fabsf(dz);
      const float npn = sqrtf(bx*bx + by*by + bz*bz) + 1e-8f;
      const float ngn = sqrtf(gx*gx + gy*gy + gz*gz) + 1e-8f;
      const float cv = -(bx*gx + by*gy + bz*gz) / (npn * ngn);
      const float mk = (inst != -1) ? 1.f : 0.f;
      l1_acc  += l1 * mk;
      cos_acc += cv * mk;
      mk_acc  += mk;
    }
  };

  auto stage = [&](float* buf, int tile) {
    const float* base = feat + (size_t)tile * 64 * 64;
    #pragma unroll
    for (int j = 0; j < 4; ++j) {
      const int u = j * 256 + tid;
      const int p = u >> 4;
      const int kl = (u & 15) << 2;
      const int kgx = kl ^ ((p & 15) << 2);
      gload16(base + p * 64 + kgx, buf + u * 4);
    }
  };
  auto lds4 = [&](const float* buf, int p, int k) -> f32x4 {
    return *(const f32x4*)(buf + p * 64 + (k ^ ((p & 15) << 2)));
  };

  int cur = 0;
  const int t0 = blockIdx.x;
  if (t0 < NTILE) {
    stage(fsbuf[0], t0);
    __syncthreads();
    for (int t = t0; t < NTILE; t += gridDim.x) {
      const int tn = t + gridDim.x;
      if (tn < NTILE) stage(fsbuf[cur ^ 1], tn);

      const float* bufc = fsbuf[cur];
      const int p = wv * 16 + col;
      const f32x4 r0 = lds4(bufc, p, kg * 8);
      const f32x4 r1 = lds4(bufc, p, kg * 8 + 4);
      const f32x4 r2 = lds4(bufc, p, 32 + kg * 8);
      const f32x4 r3 = lds4(bufc, p, 32 + kg * 8 + 4);
      union { short8v v; unsigned u[4]; } A0, A1;
      A0.u[0] = pk2(r0[0], r0[1]); A0.u[1] = pk2(r0[2], r0[3]);
      A0.u[2] = pk2(r1[0], r1[1]); A0.u[3] = pk2(r1[2], r1[3]);
      A1.u[0] = pk2(r2[0], r2[1]); A1.u[1] = pk2(r2[2], r2[3]);
      A1.u[2] = pk2(r3[0], r3[1]); A1.u[3] = pk2(r3[2], r3[3]);

      do_window(t * 4 + wv, A0.v, A1.v);

      __syncthreads();
      cur ^= 1;
    }
  }

  // ---- tail: windows 31248, 31249 ----
  if (blockIdx.x == 0 && wv < 2) {
    const int W = NWIN - 2 + wv;
    const float* fp = feat + (size_t)(W * 16 + col) * 64 + kg * 8;
    const f32x4 a0 = *(const f32x4*)(fp);
    const f32x4 a1 = *(const f32x4*)(fp + 4);
    const f32x4 a2 = *(const f32x4*)(fp + 32);
    const f32x4 a3 = *(const f32x4*)(fp + 36);
    union { short8v v; unsigned u[4]; } A0, A1;
    A0.u[0] = pk2(a0[0], a0[1]); A0.u[1] = pk2(a0[2], a0[3]);
    A0.u[2] = pk2(a1[0], a1[1]); A0.u[3] = pk2(a1[2], a1[3]);
    A1.u[0] = pk2(a2[0], a2[1]); A1.u[1] = pk2(a2[2], a2[3]);
    A1.u[2] = pk2(a3[0], a3[1]); A1.u[3] = pk2(a3[2], a3[3]);
    do_window(W, A0.v, A1.v);
  }

  float a = l1_acc, b = cos_acc, c = mk_acc;
  #pragma unroll
  for (int o = 32; o > 0; o >>= 1) {
    a += __shfl_down(a, o);
    b += __shfl_down(b, o);
    c += __shfl_down(c, o);
  }
  if (lane == 0) {
    atomicAdd(&acc[2], a);
    atomicAdd(&acc[3], b);
    atomicAdd(&acc[4], c);
  }
}

__global__ __launch_bounds__(256) void assign_kernel(
    const int* __restrict__ prop_ids, const int* __restrict__ point_ids, float* __restrict__ ws)
{
  unsigned* bitmap = (unsigned*)(ws + OFF_BITMAP);
  const int i = blockIdx.x * 256 + threadIdx.x;
  if (i < M_ASSIGN) {
    const int p = prop_ids[i];
    const int n = point_ids[i];
    atomicOr(&bitmap[p * WPR + (n >> 5)], 1u << (n & 31));
  }
}

// ---------------------------------------------------------------------------
// Per-proposal score (inline first-index search + final loss on p==0)
// ---------------------------------------------------------------------------
__global__ __launch_bounds__(1024) void score_kernel(
    const int* __restrict__ prop_ids, const int* __restrict__ point_ids,
    const float* __restrict__ ws, float* __restrict__ out)
{
  const unsigned* bitmap = (const unsigned*)(ws + OFF_BITMAP);
  const float* probs = ws + OFF_PROBS;
  const int* segp = (const int*)(ws + OFF_SEGPRED);
  __shared__ float rs[16];
  __shared__ int rc[16];
  const int p = blockIdx.x;
  const int tid = threadIdx.x;

  int lo = 0, hi = M_ASSIGN;
  while (lo < hi) { const int mid = (lo + hi) >> 1; if (prop_ids[mid] < p) lo = mid + 1; else hi = mid; }
  if (lo > M_ASSIGN - 1) lo = M_ASSIGN - 1;
  const int cp = segp[point_ids[lo]];

  float s = 0.f; int cnt = 0;
  for (int w = tid; w < WPR; w += 1024) {
    unsigned bits = bitmap[p * WPR + w];
    cnt += __popc(bits);
    while (bits) {
      const int b = __ffs(bits) - 1;
      bits &= bits - 1;
      const int n = (w << 5) + b;
      s += probs[(size_t)n * 20 + cp];
    }
  }
  #pragma unroll
  for (int o = 32; o > 0; o >>= 1) { s += __shfl_down(s, o); cnt += __shfl_down(cnt, o); }
  if ((tid & 63) == 0) { rs[tid >> 6] = s; rc[tid >> 6] = cnt; }
  __syncthreads();
  if (tid == 0) {
    float st = 0.f; int ct = 0;
    #pragma unroll
    for (int i = 0; i < 16; ++i) { st += rs[i]; ct += rc[i]; }
    const bool mk = ct > 100;
    out[1 + p]   = mk ? st / (float)(ct > 1 ? ct : 1) : 0.f;
    out[129 + p] = mk ? 1.f : 0.f;
    if (p == 0) {
      const float segl = ws[0] / fmaxf(ws[1], 1.f);
      const float d = ws[4] + 1e-8f;
      out[0] = segl + ws[2] / d + ws[3] / d;
    }
  }
}

extern "C" void kernel_launch(void* const* d_in, const int* in_sizes, int n_in,
                              void* d_out, int out_size, void* d_ws, size_t ws_size,
                              hipStream_t stream) {
  const float* feat    = (const float*)d_in[0];
  const float* coord   = (const float*)d_in[1];
  const float* cent    = (const float*)d_in[2];
  const float* w1      = (const float*)d_in[3];
  // d_in[4] = b1 : cancels through BN, unused
  const float* gamma   = (const float*)d_in[5];
  const float* beta    = (const float*)d_in[6];
  const float* w2      = (const float*)d_in[7];
  const float* b2      = (const float*)d_in[8];
  const float* seg_w   = (const float*)d_in[9];
  const float* seg_b   = (const float*)d_in[10];
  const int* segment   = (const int*)d_in[11];
  const int* instance  = (const int*)d_in[12];
  const int* prop_ids  = (const int*)d_in[13];
  const int* point_ids = (const int*)d_in[14];
  float* out = (float*)d_out;
  float* ws  = (float*)d_ws;

  // zero accumulators + BN sums + bitmap
  hipMemsetAsync(d_ws, 0, (size_t)(OFF_BITMAP + 2000000) * sizeof(float), stream);

  gemm_kernel<<<1280, 256, 0, stream>>>(feat, w1, seg_w, seg_b, segment, ws);
  bias_kernel<<<1280, 256, 0, stream>>>(feat, w1, gamma, beta, w2, b2, coord, cent, instance, ws);
  assign_kernel<<<1563, 256, 0, stream>>>(prop_ids, point_ids, ws);
  score_kernel<<<128, 1024, 0, stream>>>(prop_ids, point_ids, ws, out);
}